// Round 2
// baseline (5128.878 us; speedup 1.0000x reference)
//
#include <hip/hip_runtime.h>
#include <hip/hip_bf16.h>
#include <cstring>
#include <cstdint>

#define N_NODES 100000
#define N_EDGES 1600000
#define HID 128
#define TOT (N_NODES * HID)   // 12,800,000

// ---------------- workspace layout (bytes) ----------------
// aggbuf  f32 [N,128]   @ 0           51,200,000
// hbf/xbf bf16[N,128]   @ 51,200,000  25,600,000   (xbf aliases hbf: xbf dead before hbf written)
// counts  int [N]       @ 76,800,000     400,000
// partial int [N]       @ 77,200,000     400,000
// bsum    int [512]     @ 77,600,000       2,048
// offsets int [N+1]     @ 77,602,048     400,128
// cursor  int [N]       @ 78,002,176     400,000
// dinv    f32 [N]       @ 78,402,176     400,000
// sorted  int2[E]       @ 78,802,176  12,800,000
// total ~91.6 MB

// ---------------- helpers ----------------
__device__ __forceinline__ float2 ld2(const float* p) { return *(const float2*)p; }
__device__ __forceinline__ float2 ld2(const __hip_bfloat16* p) {
    const __hip_bfloat162 h = *(const __hip_bfloat162*)p;
    return make_float2(__bfloat162float(h.x), __bfloat162float(h.y));
}

__device__ __forceinline__ void store8(float* p, const float* v) {
    *(float4*)(p)     = make_float4(v[0], v[1], v[2], v[3]);
    *(float4*)(p + 4) = make_float4(v[4], v[5], v[6], v[7]);
}
__device__ __forceinline__ void store8(__hip_bfloat16* p, const float* v) {
    union { unsigned short us[8]; uint4 q; } u;
#pragma unroll
    for (int i = 0; i < 8; ++i) {
        __hip_bfloat16 b = __float2bfloat16(v[i]);
        unsigned short raw;
        memcpy(&raw, &b, 2);
        u.us[i] = raw;
    }
    *(uint4*)p = u.q;
}

// ---------------- cast x (f32) -> bf16, 4 elems/thread ----------------
__global__ __launch_bounds__(256) void k_cast(const float* __restrict__ x,
                                              __hip_bfloat16* __restrict__ xb) {
    int i = blockIdx.x * 256 + threadIdx.x;   // index in float4 units; TOT/4 = 3.2M
    if (i >= TOT / 4) return;
    float4 v = ((const float4*)x)[i];
    float vv[4] = {v.x, v.y, v.z, v.w};
    union { unsigned short us[4]; uint2 q; } u;
#pragma unroll
    for (int j = 0; j < 4; ++j) {
        __hip_bfloat16 b = __float2bfloat16(vv[j]);
        unsigned short raw;
        memcpy(&raw, &b, 2);
        u.us[j] = raw;
    }
    ((uint2*)xb)[i] = u.q;
}

// ---------------- CSR build ----------------
__global__ void k_count(const int* __restrict__ dst, int* __restrict__ counts) {
    int e = blockIdx.x * 256 + threadIdx.x;
    if (e < N_EDGES) atomicAdd(&counts[dst[e]], 1);
}

__global__ void k_scan_block(const int* __restrict__ counts, int* __restrict__ partial,
                             int* __restrict__ bsum) {
    __shared__ int s[256];
    int i = blockIdx.x * 256 + threadIdx.x;
    int v = (i < N_NODES) ? counts[i] : 0;
    s[threadIdx.x] = v;
    __syncthreads();
    for (int off = 1; off < 256; off <<= 1) {
        int t = (threadIdx.x >= off) ? s[threadIdx.x - off] : 0;
        __syncthreads();
        s[threadIdx.x] += t;
        __syncthreads();
    }
    if (i < N_NODES) partial[i] = s[threadIdx.x] - v;   // exclusive within block
    if (threadIdx.x == 255) bsum[blockIdx.x] = s[255];
}

__global__ void k_scan_sums(int* __restrict__ bsum, int nb) {
    __shared__ int s[512];
    int v = (threadIdx.x < nb) ? bsum[threadIdx.x] : 0;
    s[threadIdx.x] = v;
    __syncthreads();
    for (int off = 1; off < 512; off <<= 1) {
        int t = (threadIdx.x >= off) ? s[threadIdx.x - off] : 0;
        __syncthreads();
        s[threadIdx.x] += t;
        __syncthreads();
    }
    if (threadIdx.x < nb) bsum[threadIdx.x] = s[threadIdx.x] - v;  // exclusive
}

__global__ void k_finalize(const int* __restrict__ counts, const int* __restrict__ partial,
                           const int* __restrict__ bsum, int* __restrict__ offsets,
                           int* __restrict__ cursor, float* __restrict__ dinv) {
    int i = blockIdx.x * 256 + threadIdx.x;
    if (i < N_NODES) {
        int o = partial[i] + bsum[blockIdx.x];
        offsets[i] = o;
        cursor[i] = o;
        dinv[i] = rsqrtf((float)(counts[i] + 1));  // deg = in-degree + self loop
    }
    if (i == 0) offsets[N_NODES] = N_EDGES;
}

__global__ void k_scatter(const int* __restrict__ src, const int* __restrict__ dst,
                          const float* __restrict__ dinv, int* __restrict__ cursor,
                          int2* __restrict__ sorted) {
    int e = blockIdx.x * 256 + threadIdx.x;
    if (e < N_EDGES) {
        int s = src[e], d = dst[e];
        int pos = atomicAdd(&cursor[d], 1);
        float c = dinv[s] * dinv[d];
        sorted[pos] = make_int2(s, __float_as_int(c));
    }
}

// ---------------- aggregation: one wave per node, 2 features per lane ----------------
// Unrolled x4: 4 independent outstanding row-gathers per wave to hide LLC/HBM latency.
template <typename T>
__global__ __launch_bounds__(256) void k_aggregate(const T* __restrict__ X,
                                                   const int* __restrict__ offsets,
                                                   const int2* __restrict__ sorted,
                                                   const float* __restrict__ dinv,
                                                   float* __restrict__ out) {
    int node = (blockIdx.x * 256 + threadIdx.x) >> 6;
    int lane = threadIdx.x & 63;
    if (node >= N_NODES) return;
    int f = lane * 2;
    float di = dinv[node];
    float sc = di * di;
    float2 xi = ld2(X + (size_t)node * HID + f);
    float a0 = sc * xi.x, a1 = sc * xi.y;
    float b0 = 0.f, b1 = 0.f;
    int e0 = offsets[node], e1 = offsets[node + 1];
    int e = e0;
    int eu = e0 + ((e1 - e0) & ~3);
    for (; e < eu; e += 4) {
        int2 s0 = sorted[e + 0];
        int2 s1 = sorted[e + 1];
        int2 s2 = sorted[e + 2];
        int2 s3 = sorted[e + 3];
        float2 v0 = ld2(X + (size_t)s0.x * HID + f);
        float2 v1 = ld2(X + (size_t)s1.x * HID + f);
        float2 v2 = ld2(X + (size_t)s2.x * HID + f);
        float2 v3 = ld2(X + (size_t)s3.x * HID + f);
        a0 = fmaf(__int_as_float(s0.y), v0.x, a0);
        a1 = fmaf(__int_as_float(s0.y), v0.y, a1);
        b0 = fmaf(__int_as_float(s1.y), v1.x, b0);
        b1 = fmaf(__int_as_float(s1.y), v1.y, b1);
        a0 = fmaf(__int_as_float(s2.y), v2.x, a0);
        a1 = fmaf(__int_as_float(s2.y), v2.y, a1);
        b0 = fmaf(__int_as_float(s3.y), v3.x, b0);
        b1 = fmaf(__int_as_float(s3.y), v3.y, b1);
    }
    for (; e < e1; ++e) {
        int2 s = sorted[e];
        float2 v = ld2(X + (size_t)s.x * HID + f);
        a0 = fmaf(__int_as_float(s.y), v.x, a0);
        a1 = fmaf(__int_as_float(s.y), v.y, a1);
    }
    *(float2*)(out + (size_t)node * HID + f) = make_float2(a0 + b0, a1 + b1);
}

// ---------------- single GEMM: out[N,128] = A @ W + b, optional ELU ----------------
template <int ACT, typename OutT>
__global__ __launch_bounds__(256) void k_gemm(const float* __restrict__ A,
                                              const float* __restrict__ W,
                                              const float* __restrict__ bias,
                                              OutT* __restrict__ out) {
    __shared__ float Wl[16][128];
    __shared__ float Al[128][16];
    int t = threadIdx.x;
    int R = blockIdx.x * 128;
    int tx = t & 15, ty = t >> 4;
    int c0 = tx * 8;
    int r0 = ty * 8;
    float acc[8][8] = {};

    for (int k0 = 0; k0 < 128; k0 += 16) {
        {
            const float4* Wg = (const float4*)(W + k0 * 128);
            ((float4*)&Wl[0][0])[t] = Wg[t];
            ((float4*)&Wl[0][0])[t + 256] = Wg[t + 256];
        }
#pragma unroll
        for (int ii = 0; ii < 2; ++ii) {
            int id = t + ii * 256;
            int row = id >> 2, c4 = (id & 3) * 4;
            int gr = R + row;
            float4 v = make_float4(0.f, 0.f, 0.f, 0.f);
            if (gr < N_NODES) v = *(const float4*)(A + (size_t)gr * HID + k0 + c4);
            *(float4*)(&Al[row][c4]) = v;
        }
        __syncthreads();

#pragma unroll
        for (int kk4 = 0; kk4 < 4; ++kk4) {
            float4 av4[8];
#pragma unroll
            for (int j = 0; j < 8; ++j) av4[j] = *(const float4*)(&Al[r0 + j][kk4 * 4]);
            const float* av = (const float*)av4;
#pragma unroll
            for (int kk = 0; kk < 4; ++kk) {
                float4 b0 = *(const float4*)(&Wl[kk4 * 4 + kk][c0]);
                float4 b1 = *(const float4*)(&Wl[kk4 * 4 + kk][c0 + 4]);
#pragma unroll
                for (int j = 0; j < 8; ++j) {
                    float a = av[j * 4 + kk];
                    acc[j][0] = fmaf(a, b0.x, acc[j][0]);
                    acc[j][1] = fmaf(a, b0.y, acc[j][1]);
                    acc[j][2] = fmaf(a, b0.z, acc[j][2]);
                    acc[j][3] = fmaf(a, b0.w, acc[j][3]);
                    acc[j][4] = fmaf(a, b1.x, acc[j][4]);
                    acc[j][5] = fmaf(a, b1.y, acc[j][5]);
                    acc[j][6] = fmaf(a, b1.z, acc[j][6]);
                    acc[j][7] = fmaf(a, b1.w, acc[j][7]);
                }
            }
        }
        __syncthreads();
    }

    float bcol[8];
#pragma unroll
    for (int c = 0; c < 8; ++c) bcol[c] = bias[c0 + c];
#pragma unroll
    for (int j = 0; j < 8; ++j) {
        int gr = R + r0 + j;
        if (gr >= N_NODES) continue;
        float v[8];
#pragma unroll
        for (int c = 0; c < 8; ++c) {
            float vv = acc[j][c] + bcol[c];
            if (ACT == 1) vv = (vv > 0.f) ? vv : expm1f(vv);  // ELU(alpha=1)
            v[c] = vv;
        }
        store8(out + (size_t)gr * HID + c0, v);
    }
}

// ---------------- Threefry-2x32 (20 rounds), key = (0, 42) ----------------
__device__ __forceinline__ unsigned rotl32(unsigned x, int r) {
    return (x << r) | (x >> (32 - r));
}

__device__ __forceinline__ void threefry2x32(unsigned x0, unsigned x1, unsigned& o0,
                                             unsigned& o1) {
    const unsigned ks0 = 0u, ks1 = 42u, ks2 = 0x1BD11BDAu ^ 42u;
    x0 += ks0;
    x1 += ks1;
    x0 += x1; x1 = rotl32(x1, 13); x1 ^= x0;
    x0 += x1; x1 = rotl32(x1, 15); x1 ^= x0;
    x0 += x1; x1 = rotl32(x1, 26); x1 ^= x0;
    x0 += x1; x1 = rotl32(x1, 6);  x1 ^= x0;
    x0 += ks1; x1 += ks2 + 1u;
    x0 += x1; x1 = rotl32(x1, 17); x1 ^= x0;
    x0 += x1; x1 = rotl32(x1, 29); x1 ^= x0;
    x0 += x1; x1 = rotl32(x1, 16); x1 ^= x0;
    x0 += x1; x1 = rotl32(x1, 24); x1 ^= x0;
    x0 += ks2; x1 += ks0 + 2u;
    x0 += x1; x1 = rotl32(x1, 13); x1 ^= x0;
    x0 += x1; x1 = rotl32(x1, 15); x1 ^= x0;
    x0 += x1; x1 = rotl32(x1, 26); x1 ^= x0;
    x0 += x1; x1 = rotl32(x1, 6);  x1 ^= x0;
    x0 += ks0; x1 += ks1 + 3u;
    x0 += x1; x1 = rotl32(x1, 17); x1 ^= x0;
    x0 += x1; x1 = rotl32(x1, 29); x1 ^= x0;
    x0 += x1; x1 = rotl32(x1, 16); x1 ^= x0;
    x0 += x1; x1 = rotl32(x1, 24); x1 ^= x0;
    x0 += ks1; x1 += ks2 + 4u;
    x0 += x1; x1 = rotl32(x1, 13); x1 ^= x0;
    x0 += x1; x1 = rotl32(x1, 15); x1 ^= x0;
    x0 += x1; x1 = rotl32(x1, 26); x1 ^= x0;
    x0 += x1; x1 = rotl32(x1, 6);  x1 ^= x0;
    x0 += ks2; x1 += ks0 + 5u;
    o0 = x0;
    o1 = x1;
}

// XLA ErfInv (f32, Giles) — matches the expansion used by jax.random.normal.
__device__ __forceinline__ float erfinv_f32(float x) {
    float w = -log1pf(-x * x);
    float p;
    if (w < 5.0f) {
        w -= 2.5f;
        p = 2.81022636e-08f;
        p = fmaf(p, w, 3.43273939e-07f);
        p = fmaf(p, w, -3.5233877e-06f);
        p = fmaf(p, w, -4.39150654e-06f);
        p = fmaf(p, w, 0.00021858087f);
        p = fmaf(p, w, -0.00125372503f);
        p = fmaf(p, w, -0.00417768164f);
        p = fmaf(p, w, 0.246640727f);
        p = fmaf(p, w, 1.50140941f);
    } else {
        w = sqrtf(w) - 3.0f;
        p = -0.000200214257f;
        p = fmaf(p, w, 0.000100950558f);
        p = fmaf(p, w, 0.00134934322f);
        p = fmaf(p, w, -0.00367342844f);
        p = fmaf(p, w, 0.00573950773f);
        p = fmaf(p, w, -0.0076224613f);
        p = fmaf(p, w, 0.00943887047f);
        p = fmaf(p, w, 1.00167406f);
        p = fmaf(p, w, 2.83297682f);
    }
    return p * x;
}

// ---------------- fused dual GEMM (mu, logvar) + reparameterize epilogue -------------
// mu = A@Wm + bm ; lv = A@Wl + bl ; z = mu + eps*exp(0.5*lv)
__global__ __launch_bounds__(256) void k_gemm_mulv(const float* __restrict__ A,
                                                   const float* __restrict__ Wm,
                                                   const float* __restrict__ bm,
                                                   const float* __restrict__ Wl,
                                                   const float* __restrict__ bl,
                                                   float* __restrict__ z,
                                                   float* __restrict__ mu,
                                                   float* __restrict__ lv) {
    __shared__ float Wml[16][128];
    __shared__ float Wll[16][128];
    __shared__ float Al[128][16];
    int t = threadIdx.x;
    int R = blockIdx.x * 128;
    int tx = t & 15, ty = t >> 4;
    int c0 = tx * 8;
    int r0 = ty * 8;
    float accm[8][8] = {};
    float accl[8][8] = {};

    for (int k0 = 0; k0 < 128; k0 += 16) {
        {
            const float4* Wmg = (const float4*)(Wm + k0 * 128);
            const float4* Wlg = (const float4*)(Wl + k0 * 128);
            ((float4*)&Wml[0][0])[t] = Wmg[t];
            ((float4*)&Wml[0][0])[t + 256] = Wmg[t + 256];
            ((float4*)&Wll[0][0])[t] = Wlg[t];
            ((float4*)&Wll[0][0])[t + 256] = Wlg[t + 256];
        }
#pragma unroll
        for (int ii = 0; ii < 2; ++ii) {
            int id = t + ii * 256;
            int row = id >> 2, c4 = (id & 3) * 4;
            int gr = R + row;
            float4 v = make_float4(0.f, 0.f, 0.f, 0.f);
            if (gr < N_NODES) v = *(const float4*)(A + (size_t)gr * HID + k0 + c4);
            *(float4*)(&Al[row][c4]) = v;
        }
        __syncthreads();

#pragma unroll
        for (int kk4 = 0; kk4 < 4; ++kk4) {
            float4 av4[8];
#pragma unroll
            for (int j = 0; j < 8; ++j) av4[j] = *(const float4*)(&Al[r0 + j][kk4 * 4]);
            const float* av = (const float*)av4;
#pragma unroll
            for (int kk = 0; kk < 4; ++kk) {
                float4 m0 = *(const float4*)(&Wml[kk4 * 4 + kk][c0]);
                float4 m1 = *(const float4*)(&Wml[kk4 * 4 + kk][c0 + 4]);
                float4 l0 = *(const float4*)(&Wll[kk4 * 4 + kk][c0]);
                float4 l1 = *(const float4*)(&Wll[kk4 * 4 + kk][c0 + 4]);
#pragma unroll
                for (int j = 0; j < 8; ++j) {
                    float a = av[j * 4 + kk];
                    accm[j][0] = fmaf(a, m0.x, accm[j][0]);
                    accm[j][1] = fmaf(a, m0.y, accm[j][1]);
                    accm[j][2] = fmaf(a, m0.z, accm[j][2]);
                    accm[j][3] = fmaf(a, m0.w, accm[j][3]);
                    accm[j][4] = fmaf(a, m1.x, accm[j][4]);
                    accm[j][5] = fmaf(a, m1.y, accm[j][5]);
                    accm[j][6] = fmaf(a, m1.z, accm[j][6]);
                    accm[j][7] = fmaf(a, m1.w, accm[j][7]);
                    accl[j][0] = fmaf(a, l0.x, accl[j][0]);
                    accl[j][1] = fmaf(a, l0.y, accl[j][1]);
                    accl[j][2] = fmaf(a, l0.z, accl[j][2]);
                    accl[j][3] = fmaf(a, l0.w, accl[j][3]);
                    accl[j][4] = fmaf(a, l1.x, accl[j][4]);
                    accl[j][5] = fmaf(a, l1.y, accl[j][5]);
                    accl[j][6] = fmaf(a, l1.z, accl[j][6]);
                    accl[j][7] = fmaf(a, l1.w, accl[j][7]);
                }
            }
        }
        __syncthreads();
    }

    float bmc[8], blc[8];
#pragma unroll
    for (int c = 0; c < 8; ++c) { bmc[c] = bm[c0 + c]; blc[c] = bl[c0 + c]; }

#pragma unroll
    for (int j = 0; j < 8; ++j) {
        int gr = R + r0 + j;
        if (gr >= N_NODES) continue;
        float vm[8], vl[8], vz[8];
#pragma unroll
        for (int c = 0; c < 8; ++c) {
            float m = accm[j][c] + bmc[c];
            float l = accl[j][c] + blc[c];
            unsigned idx = (unsigned)gr * 128u + (unsigned)(c0 + c);
            unsigned o0, o1;
            threefry2x32(0u, idx, o0, o1);
            unsigned bits = o0 ^ o1;
            float fb = __uint_as_float((bits >> 9) | 0x3f800000u) - 1.0f;
            float u = fmaxf(fb * 2.0f - 0.99999994f, -0.99999994f);
            float eps = 1.41421356f * erfinv_f32(u);
            vm[c] = m;
            vl[c] = l;
            vz[c] = fmaf(eps, expf(0.5f * l), m);
        }
        store8(mu + (size_t)gr * HID + c0, vm);
        store8(lv + (size_t)gr * HID + c0, vl);
        store8(z + (size_t)gr * HID + c0, vz);
    }
}

// ---------------- launch ----------------
extern "C" void kernel_launch(void* const* d_in, const int* in_sizes, int n_in,
                              void* d_out, int out_size, void* d_ws, size_t ws_size,
                              hipStream_t stream) {
    const float* x = (const float*)d_in[0];
    const int* ei = (const int*)d_in[1];
    const float* W1 = (const float*)d_in[2];
    const float* b1 = (const float*)d_in[3];
    const float* Wmu = (const float*)d_in[4];
    const float* bmu = (const float*)d_in[5];
    const float* Wlv = (const float*)d_in[6];
    const float* blv = (const float*)d_in[7];

    float* z = (float*)d_out;
    float* mu = z + (size_t)TOT;
    float* lv = z + 2 * (size_t)TOT;

    char* ws = (char*)d_ws;
    float* aggbuf = (float*)(ws + 0ull);
    __hip_bfloat16* hbf = (__hip_bfloat16*)(ws + 51200000ull);  // also xbf (aliased)
    __hip_bfloat16* xbf = hbf;
    int* counts = (int*)(ws + 76800000ull);
    int* partial = (int*)(ws + 77200000ull);
    int* bsum = (int*)(ws + 77600000ull);
    int* offsets = (int*)(ws + 77602048ull);
    int* cursor = (int*)(ws + 78002176ull);
    float* dinv = (float*)(ws + 78402176ull);
    int2* sorted = (int2*)(ws + 78802176ull);

    const int* src = ei;
    const int* dst = ei + N_EDGES;

    const int NBLK = (N_NODES + 255) / 256;  // 391

    hipMemsetAsync(counts, 0, N_NODES * sizeof(int), stream);
    k_cast<<<(TOT / 4 + 255) / 256, 256, 0, stream>>>(x, xbf);
    k_count<<<(N_EDGES + 255) / 256, 256, 0, stream>>>(dst, counts);
    k_scan_block<<<NBLK, 256, 0, stream>>>(counts, partial, bsum);
    k_scan_sums<<<1, 512, 0, stream>>>(bsum, NBLK);
    k_finalize<<<NBLK, 256, 0, stream>>>(counts, partial, bsum, offsets, cursor, dinv);
    k_scatter<<<(N_EDGES + 255) / 256, 256, 0, stream>>>(src, dst, dinv, cursor, sorted);

    // layer 1: xa = Agg(xbf); h = elu(xa @ W1 + b1)  (h stored bf16; overwrites xbf — dead)
    k_aggregate<__hip_bfloat16><<<(N_NODES * 64 + 255) / 256, 256, 0, stream>>>(
        xbf, offsets, sorted, dinv, aggbuf);
    k_gemm<1, __hip_bfloat16><<<(N_NODES + 127) / 128, 256, 0, stream>>>(aggbuf, W1, b1, hbf);

    // layer 2: ha = Agg(h); fused mu/lv GEMM + reparameterize
    k_aggregate<__hip_bfloat16><<<(N_NODES * 64 + 255) / 256, 256, 0, stream>>>(
        hbf, offsets, sorted, dinv, aggbuf);
    k_gemm_mulv<<<(N_NODES + 127) / 128, 256, 0, stream>>>(aggbuf, Wmu, bmu, Wlv, blv, z, mu, lv);
}

// Round 3
// 2434.359 us; speedup vs baseline: 2.1069x; 2.1069x over previous
//
#include <hip/hip_runtime.h>
#include <hip/hip_bf16.h>
#include <cstring>
#include <cstdint>

#define N_NODES 100000
#define N_EDGES 1600000
#define HID 128
#define TOT (N_NODES * HID)   // 12,800,000

// ---------------- workspace layout (bytes) ----------------
// aggbuf  f32 [N,128]   @ 0           51,200,000
// hbf/xbf bf16[N,128]   @ 51,200,000  25,600,000   (xbf aliases hbf: xbf dead before hbf written)
// counts  int [N]       @ 76,800,000     400,000
// partial int [N]       @ 77,200,000     400,000
// bsum    int [512]     @ 77,600,000       2,048
// offsets int [N+1]     @ 77,602,048     400,128
// cursor  int [N]       @ 78,002,176     400,000
// dinv    f32 [N]       @ 78,402,176     400,000
// sorted  int2[E]       @ 78,802,176  12,800,000
// total ~91.6 MB

// ---------------- helpers ----------------
__device__ __forceinline__ float2 ld2(const __hip_bfloat16* p) {
    const __hip_bfloat162 h = *(const __hip_bfloat162*)p;
    return make_float2(__bfloat162float(h.x), __bfloat162float(h.y));
}

__device__ __forceinline__ void store4f(float* p, float a, float b, float c, float d) {
    *(float4*)p = make_float4(a, b, c, d);
}
__device__ __forceinline__ void store4bf(__hip_bfloat16* p, float a, float b, float c,
                                         float d) {
    union { unsigned short us[4]; uint2 q; } u;
    float v[4] = {a, b, c, d};
#pragma unroll
    for (int i = 0; i < 4; ++i) {
        __hip_bfloat16 bb = __float2bfloat16(v[i]);
        unsigned short raw;
        memcpy(&raw, &bb, 2);
        u.us[i] = raw;
    }
    *(uint2*)p = u.q;
}

// ---------------- cast x (f32) -> bf16, 4 elems/thread ----------------
__global__ __launch_bounds__(256) void k_cast(const float* __restrict__ x,
                                              __hip_bfloat16* __restrict__ xb) {
    int i = blockIdx.x * 256 + threadIdx.x;   // float4 units; TOT/4 = 3.2M
    if (i >= TOT / 4) return;
    float4 v = ((const float4*)x)[i];
    float vv[4] = {v.x, v.y, v.z, v.w};
    union { unsigned short us[4]; uint2 q; } u;
#pragma unroll
    for (int j = 0; j < 4; ++j) {
        __hip_bfloat16 b = __float2bfloat16(vv[j]);
        unsigned short raw;
        memcpy(&raw, &b, 2);
        u.us[j] = raw;
    }
    ((uint2*)xb)[i] = u.q;
}

// ---------------- CSR build ----------------
__global__ void k_count(const int* __restrict__ dst, int* __restrict__ counts) {
    int e = blockIdx.x * 256 + threadIdx.x;
    if (e < N_EDGES) atomicAdd(&counts[dst[e]], 1);
}

__global__ void k_scan_block(const int* __restrict__ counts, int* __restrict__ partial,
                             int* __restrict__ bsum) {
    __shared__ int s[256];
    int i = blockIdx.x * 256 + threadIdx.x;
    int v = (i < N_NODES) ? counts[i] : 0;
    s[threadIdx.x] = v;
    __syncthreads();
    for (int off = 1; off < 256; off <<= 1) {
        int t = (threadIdx.x >= off) ? s[threadIdx.x - off] : 0;
        __syncthreads();
        s[threadIdx.x] += t;
        __syncthreads();
    }
    if (i < N_NODES) partial[i] = s[threadIdx.x] - v;   // exclusive within block
    if (threadIdx.x == 255) bsum[blockIdx.x] = s[255];
}

__global__ void k_scan_sums(int* __restrict__ bsum, int nb) {
    __shared__ int s[512];
    int v = (threadIdx.x < nb) ? bsum[threadIdx.x] : 0;
    s[threadIdx.x] = v;
    __syncthreads();
    for (int off = 1; off < 512; off <<= 1) {
        int t = (threadIdx.x >= off) ? s[threadIdx.x - off] : 0;
        __syncthreads();
        s[threadIdx.x] += t;
        __syncthreads();
    }
    if (threadIdx.x < nb) bsum[threadIdx.x] = s[threadIdx.x] - v;  // exclusive
}

__global__ void k_finalize(const int* __restrict__ counts, const int* __restrict__ partial,
                           const int* __restrict__ bsum, int* __restrict__ offsets,
                           int* __restrict__ cursor, float* __restrict__ dinv) {
    int i = blockIdx.x * 256 + threadIdx.x;
    if (i < N_NODES) {
        int o = partial[i] + bsum[blockIdx.x];
        offsets[i] = o;
        cursor[i] = o;
        dinv[i] = rsqrtf((float)(counts[i] + 1));  // deg = in-degree + self loop
    }
    if (i == 0) offsets[N_NODES] = N_EDGES;
}

__global__ void k_scatter(const int* __restrict__ src, const int* __restrict__ dst,
                          const float* __restrict__ dinv, int* __restrict__ cursor,
                          int2* __restrict__ sorted) {
    int e = blockIdx.x * 256 + threadIdx.x;
    if (e < N_EDGES) {
        int s = src[e], d = dst[e];
        int pos = atomicAdd(&cursor[d], 1);
        float c = dinv[s] * dinv[d];
        sorted[pos] = make_int2(s, __float_as_int(c));
    }
}

// ---------------- aggregation: one wave per node, 2 features per lane ----------------
// Unrolled x4: 4 independent outstanding row-gathers per wave to hide LLC/HBM latency.
template <typename T>
__global__ __launch_bounds__(256) void k_aggregate(const T* __restrict__ X,
                                                   const int* __restrict__ offsets,
                                                   const int2* __restrict__ sorted,
                                                   const float* __restrict__ dinv,
                                                   float* __restrict__ out) {
    int node = (blockIdx.x * 256 + threadIdx.x) >> 6;
    int lane = threadIdx.x & 63;
    if (node >= N_NODES) return;
    int f = lane * 2;
    float di = dinv[node];
    float sc = di * di;
    float2 xi = ld2(X + (size_t)node * HID + f);
    float a0 = sc * xi.x, a1 = sc * xi.y;
    float b0 = 0.f, b1 = 0.f;
    int e0 = offsets[node], e1 = offsets[node + 1];
    int e = e0;
    int eu = e0 + ((e1 - e0) & ~3);
    for (; e < eu; e += 4) {
        int2 s0 = sorted[e + 0];
        int2 s1 = sorted[e + 1];
        int2 s2 = sorted[e + 2];
        int2 s3 = sorted[e + 3];
        float2 v0 = ld2(X + (size_t)s0.x * HID + f);
        float2 v1 = ld2(X + (size_t)s1.x * HID + f);
        float2 v2 = ld2(X + (size_t)s2.x * HID + f);
        float2 v3 = ld2(X + (size_t)s3.x * HID + f);
        a0 = fmaf(__int_as_float(s0.y), v0.x, a0);
        a1 = fmaf(__int_as_float(s0.y), v0.y, a1);
        b0 = fmaf(__int_as_float(s1.y), v1.x, b0);
        b1 = fmaf(__int_as_float(s1.y), v1.y, b1);
        a0 = fmaf(__int_as_float(s2.y), v2.x, a0);
        a1 = fmaf(__int_as_float(s2.y), v2.y, a1);
        b0 = fmaf(__int_as_float(s3.y), v3.x, b0);
        b1 = fmaf(__int_as_float(s3.y), v3.y, b1);
    }
    for (; e < e1; ++e) {
        int2 s = sorted[e];
        float2 v = ld2(X + (size_t)s.x * HID + f);
        a0 = fmaf(__int_as_float(s.y), v.x, a0);
        a1 = fmaf(__int_as_float(s.y), v.y, a1);
    }
    *(float2*)(out + (size_t)node * HID + f) = make_float2(a0 + b0, a1 + b1);
}

// ============ shared GEMM plumbing ============
// block: 256 threads, tile 128 rows x 128 cols, K chunked by 16 via LDS.
// Al is K-MAJOR [16][132] (pad +4): compute reads are 16-lane broadcasts on distinct
// banks; staging writes are 2-way (free). Thread (tx,ty) computes 8 rows (ty*8..)
// x cols {tx*4..+3, 64+tx*4..+3}: W reads are 2-way (free) instead of 4-way.
#define GEMM_PROLOGUE()                                                        \
    __shared__ float Wl[16][132];                                              \
    __shared__ float Al[16][132];                                              \
    int t = threadIdx.x;                                                       \
    int R = blockIdx.x * 128;                                                  \
    int tx = t & 15, ty = t >> 4;                                              \
    int cA = tx * 4;                                                           \
    int r0 = ty * 8;                                                           \
    float acc[8][8] = {};

#define GEMM_STAGE_W(Wp)                                                       \
    {                                                                          \
        _Pragma("unroll") for (int ii = 0; ii < 2; ++ii) {                     \
            int id = t + ii * 256;                                             \
            int row = id >> 5, g = id & 31;                                    \
            float4 v = *(const float4*)((Wp) + (k0 + row) * 128 + g * 4);      \
            *(float4*)(&Wl[row][g * 4]) = v;                                   \
        }                                                                      \
    }

#define GEMM_STAGE_A(Ap)                                                       \
    {                                                                          \
        _Pragma("unroll") for (int ii = 0; ii < 2; ++ii) {                     \
            int id = t + ii * 256;                                             \
            int row = id >> 2, c4 = (id & 3) * 4;                              \
            int gr = R + row;                                                  \
            float4 v = make_float4(0.f, 0.f, 0.f, 0.f);                        \
            if (gr < N_NODES) v = *(const float4*)((Ap) + (size_t)gr * HID + k0 + c4); \
            Al[c4 + 0][row] = v.x;                                             \
            Al[c4 + 1][row] = v.y;                                             \
            Al[c4 + 2][row] = v.z;                                             \
            Al[c4 + 3][row] = v.w;                                             \
        }                                                                      \
    }

#define GEMM_COMPUTE()                                                         \
    _Pragma("unroll") for (int kk = 0; kk < 16; ++kk) {                        \
        float4 alo = *(const float4*)(&Al[kk][r0]);                            \
        float4 ahi = *(const float4*)(&Al[kk][r0 + 4]);                        \
        float4 wlo = *(const float4*)(&Wl[kk][cA]);                            \
        float4 whi = *(const float4*)(&Wl[kk][cA + 64]);                       \
        float ar[8] = {alo.x, alo.y, alo.z, alo.w, ahi.x, ahi.y, ahi.z, ahi.w};\
        _Pragma("unroll") for (int j = 0; j < 8; ++j) {                        \
            acc[j][0] = fmaf(ar[j], wlo.x, acc[j][0]);                         \
            acc[j][1] = fmaf(ar[j], wlo.y, acc[j][1]);                         \
            acc[j][2] = fmaf(ar[j], wlo.z, acc[j][2]);                         \
            acc[j][3] = fmaf(ar[j], wlo.w, acc[j][3]);                         \
            acc[j][4] = fmaf(ar[j], whi.x, acc[j][4]);                         \
            acc[j][5] = fmaf(ar[j], whi.y, acc[j][5]);                         \
            acc[j][6] = fmaf(ar[j], whi.z, acc[j][6]);                         \
            acc[j][7] = fmaf(ar[j], whi.w, acc[j][7]);                         \
        }                                                                      \
    }

// ---------------- GEMM 1: h = elu(A @ W1 + b1), bf16 out ----------------
__global__ __launch_bounds__(256) void k_gemm_elu(const float* __restrict__ A,
                                                  const float* __restrict__ W,
                                                  const float* __restrict__ bias,
                                                  __hip_bfloat16* __restrict__ out) {
    GEMM_PROLOGUE()
    for (int k0 = 0; k0 < 128; k0 += 16) {
        GEMM_STAGE_W(W)
        GEMM_STAGE_A(A)
        __syncthreads();
        GEMM_COMPUTE()
        __syncthreads();
    }
    float blo[4], bhi[4];
#pragma unroll
    for (int c = 0; c < 4; ++c) { blo[c] = bias[cA + c]; bhi[c] = bias[cA + 64 + c]; }
#pragma unroll
    for (int j = 0; j < 8; ++j) {
        int gr = R + r0 + j;
        if (gr >= N_NODES) continue;
        float v[8];
#pragma unroll
        for (int c = 0; c < 4; ++c) {
            float a = acc[j][c] + blo[c];
            float b = acc[j][4 + c] + bhi[c];
            v[c] = (a > 0.f) ? a : expm1f(a);
            v[4 + c] = (b > 0.f) ? b : expm1f(b);
        }
        store4bf(out + (size_t)gr * HID + cA, v[0], v[1], v[2], v[3]);
        store4bf(out + (size_t)gr * HID + cA + 64, v[4], v[5], v[6], v[7]);
    }
}

// ---------------- GEMM 2: mu = A @ Wm + bm, f32 out ----------------
__global__ __launch_bounds__(256) void k_gemm_mu(const float* __restrict__ A,
                                                 const float* __restrict__ W,
                                                 const float* __restrict__ bias,
                                                 float* __restrict__ out) {
    GEMM_PROLOGUE()
    for (int k0 = 0; k0 < 128; k0 += 16) {
        GEMM_STAGE_W(W)
        GEMM_STAGE_A(A)
        __syncthreads();
        GEMM_COMPUTE()
        __syncthreads();
    }
    float blo[4], bhi[4];
#pragma unroll
    for (int c = 0; c < 4; ++c) { blo[c] = bias[cA + c]; bhi[c] = bias[cA + 64 + c]; }
#pragma unroll
    for (int j = 0; j < 8; ++j) {
        int gr = R + r0 + j;
        if (gr >= N_NODES) continue;
        store4f(out + (size_t)gr * HID + cA, acc[j][0] + blo[0], acc[j][1] + blo[1],
                acc[j][2] + blo[2], acc[j][3] + blo[3]);
        store4f(out + (size_t)gr * HID + cA + 64, acc[j][4] + bhi[0], acc[j][5] + bhi[1],
                acc[j][6] + bhi[2], acc[j][7] + bhi[3]);
    }
}

// ---------------- Threefry-2x32 (20 rounds), key = (0, 42) ----------------
__device__ __forceinline__ unsigned rotl32(unsigned x, int r) {
    return (x << r) | (x >> (32 - r));
}

__device__ __forceinline__ void threefry2x32(unsigned x0, unsigned x1, unsigned& o0,
                                             unsigned& o1) {
    const unsigned ks0 = 0u, ks1 = 42u, ks2 = 0x1BD11BDAu ^ 42u;
    x0 += ks0;
    x1 += ks1;
    x0 += x1; x1 = rotl32(x1, 13); x1 ^= x0;
    x0 += x1; x1 = rotl32(x1, 15); x1 ^= x0;
    x0 += x1; x1 = rotl32(x1, 26); x1 ^= x0;
    x0 += x1; x1 = rotl32(x1, 6);  x1 ^= x0;
    x0 += ks1; x1 += ks2 + 1u;
    x0 += x1; x1 = rotl32(x1, 17); x1 ^= x0;
    x0 += x1; x1 = rotl32(x1, 29); x1 ^= x0;
    x0 += x1; x1 = rotl32(x1, 16); x1 ^= x0;
    x0 += x1; x1 = rotl32(x1, 24); x1 ^= x0;
    x0 += ks2; x1 += ks0 + 2u;
    x0 += x1; x1 = rotl32(x1, 13); x1 ^= x0;
    x0 += x1; x1 = rotl32(x1, 15); x1 ^= x0;
    x0 += x1; x1 = rotl32(x1, 26); x1 ^= x0;
    x0 += x1; x1 = rotl32(x1, 6);  x1 ^= x0;
    x0 += ks0; x1 += ks1 + 3u;
    x0 += x1; x1 = rotl32(x1, 17); x1 ^= x0;
    x0 += x1; x1 = rotl32(x1, 29); x1 ^= x0;
    x0 += x1; x1 = rotl32(x1, 16); x1 ^= x0;
    x0 += x1; x1 = rotl32(x1, 24); x1 ^= x0;
    x0 += ks1; x1 += ks2 + 4u;
    x0 += x1; x1 = rotl32(x1, 13); x1 ^= x0;
    x0 += x1; x1 = rotl32(x1, 15); x1 ^= x0;
    x0 += x1; x1 = rotl32(x1, 26); x1 ^= x0;
    x0 += x1; x1 = rotl32(x1, 6);  x1 ^= x0;
    x0 += ks2; x1 += ks0 + 5u;
    o0 = x0;
    o1 = x1;
}

// XLA ErfInv (f32, Giles) — matches the expansion used by jax.random.normal.
__device__ __forceinline__ float erfinv_f32(float x) {
    float w = -log1pf(-x * x);
    float p;
    if (w < 5.0f) {
        w -= 2.5f;
        p = 2.81022636e-08f;
        p = fmaf(p, w, 3.43273939e-07f);
        p = fmaf(p, w, -3.5233877e-06f);
        p = fmaf(p, w, -4.39150654e-06f);
        p = fmaf(p, w, 0.00021858087f);
        p = fmaf(p, w, -0.00125372503f);
        p = fmaf(p, w, -0.00417768164f);
        p = fmaf(p, w, 0.246640727f);
        p = fmaf(p, w, 1.50140941f);
    } else {
        w = sqrtf(w) - 3.0f;
        p = -0.000200214257f;
        p = fmaf(p, w, 0.000100950558f);
        p = fmaf(p, w, 0.00134934322f);
        p = fmaf(p, w, -0.00367342844f);
        p = fmaf(p, w, 0.00573950773f);
        p = fmaf(p, w, -0.0076224613f);
        p = fmaf(p, w, 0.00943887047f);
        p = fmaf(p, w, 1.00167406f);
        p = fmaf(p, w, 2.83297682f);
    }
    return p * x;
}

__device__ __forceinline__ float eps_normal(unsigned idx) {
    unsigned o0, o1;
    threefry2x32(0u, idx, o0, o1);
    unsigned bits = o0 ^ o1;
    float fb = __uint_as_float((bits >> 9) | 0x3f800000u) - 1.0f;
    float u = fmaxf(fb * 2.0f - 0.99999994f, -0.99999994f);
    return 1.41421356f * erfinv_f32(u);
}

// ---------------- GEMM 3: lv = A @ Wl + bl; epilogue reads mu, emits z ----------------
// z = mu + eps * exp(0.5*lv). Single accumulator tile; mu comes from global (written
// by k_gemm_mu, ordered on the same stream).
__global__ __launch_bounds__(256) void k_gemm_lv_z(const float* __restrict__ A,
                                                   const float* __restrict__ W,
                                                   const float* __restrict__ bias,
                                                   const float* __restrict__ mu,
                                                   float* __restrict__ lv,
                                                   float* __restrict__ z) {
    GEMM_PROLOGUE()
    for (int k0 = 0; k0 < 128; k0 += 16) {
        GEMM_STAGE_W(W)
        GEMM_STAGE_A(A)
        __syncthreads();
        GEMM_COMPUTE()
        __syncthreads();
    }
    float blo[4], bhi[4];
#pragma unroll
    for (int c = 0; c < 4; ++c) { blo[c] = bias[cA + c]; bhi[c] = bias[cA + 64 + c]; }
#pragma unroll
    for (int j = 0; j < 8; ++j) {
        int gr = R + r0 + j;
        if (gr >= N_NODES) continue;
        float4 mlo = *(const float4*)(mu + (size_t)gr * HID + cA);
        float4 mhi = *(const float4*)(mu + (size_t)gr * HID + cA + 64);
        float ml[8] = {mlo.x, mlo.y, mlo.z, mlo.w, mhi.x, mhi.y, mhi.z, mhi.w};
        float l[8], zz[8];
#pragma unroll
        for (int c = 0; c < 4; ++c) {
            l[c] = acc[j][c] + blo[c];
            l[4 + c] = acc[j][4 + c] + bhi[c];
        }
#pragma unroll
        for (int c = 0; c < 8; ++c) {
            int col = (c < 4) ? (cA + c) : (cA + 60 + c);   // c>=4 -> cA+64+(c-4)
            unsigned idx = (unsigned)gr * 128u + (unsigned)col;
            zz[c] = fmaf(eps_normal(idx), expf(0.5f * l[c]), ml[c]);
        }
        store4f(lv + (size_t)gr * HID + cA, l[0], l[1], l[2], l[3]);
        store4f(lv + (size_t)gr * HID + cA + 64, l[4], l[5], l[6], l[7]);
        store4f(z + (size_t)gr * HID + cA, zz[0], zz[1], zz[2], zz[3]);
        store4f(z + (size_t)gr * HID + cA + 64, zz[4], zz[5], zz[6], zz[7]);
    }
}

// ---------------- launch ----------------
extern "C" void kernel_launch(void* const* d_in, const int* in_sizes, int n_in,
                              void* d_out, int out_size, void* d_ws, size_t ws_size,
                              hipStream_t stream) {
    const float* x = (const float*)d_in[0];
    const int* ei = (const int*)d_in[1];
    const float* W1 = (const float*)d_in[2];
    const float* b1 = (const float*)d_in[3];
    const float* Wmu = (const float*)d_in[4];
    const float* bmu = (const float*)d_in[5];
    const float* Wlv = (const float*)d_in[6];
    const float* blv = (const float*)d_in[7];

    float* z = (float*)d_out;
    float* mu = z + (size_t)TOT;
    float* lv = z + 2 * (size_t)TOT;

    char* ws = (char*)d_ws;
    float* aggbuf = (float*)(ws + 0ull);
    __hip_bfloat16* hbf = (__hip_bfloat16*)(ws + 51200000ull);  // also xbf (aliased)
    __hip_bfloat16* xbf = hbf;
    int* counts = (int*)(ws + 76800000ull);
    int* partial = (int*)(ws + 77200000ull);
    int* bsum = (int*)(ws + 77600000ull);
    int* offsets = (int*)(ws + 77602048ull);
    int* cursor = (int*)(ws + 78002176ull);
    float* dinv = (float*)(ws + 78402176ull);
    int2* sorted = (int2*)(ws + 78802176ull);

    const int* src = ei;
    const int* dst = ei + N_EDGES;

    const int NBLK = (N_NODES + 255) / 256;  // 391
    const int GB = (N_NODES + 127) / 128;    // 782

    hipMemsetAsync(counts, 0, N_NODES * sizeof(int), stream);
    k_cast<<<(TOT / 4 + 255) / 256, 256, 0, stream>>>(x, xbf);
    k_count<<<(N_EDGES + 255) / 256, 256, 0, stream>>>(dst, counts);
    k_scan_block<<<NBLK, 256, 0, stream>>>(counts, partial, bsum);
    k_scan_sums<<<1, 512, 0, stream>>>(bsum, NBLK);
    k_finalize<<<NBLK, 256, 0, stream>>>(counts, partial, bsum, offsets, cursor, dinv);
    k_scatter<<<(N_EDGES + 255) / 256, 256, 0, stream>>>(src, dst, dinv, cursor, sorted);

    // layer 1: xa = Agg(xbf); h = elu(xa @ W1 + b1)  (h bf16; overwrites xbf — dead)
    k_aggregate<__hip_bfloat16><<<(N_NODES * 64 + 255) / 256, 256, 0, stream>>>(
        xbf, offsets, sorted, dinv, aggbuf);
    k_gemm_elu<<<GB, 256, 0, stream>>>(aggbuf, W1, b1, hbf);

    // layer 2: ha = Agg(h); mu = ha@Wmu+bmu; lv = ha@Wlv+blv; z fused into lv epilogue
    k_aggregate<__hip_bfloat16><<<(N_NODES * 64 + 255) / 256, 256, 0, stream>>>(
        hbf, offsets, sorted, dinv, aggbuf);
    k_gemm_mu<<<GB, 256, 0, stream>>>(aggbuf, Wmu, bmu, mu);
    k_gemm_lv_z<<<GB, 256, 0, stream>>>(aggbuf, Wlv, blv, mu, lv, z);
}